// Round 12
// baseline (376.408 us; speedup 1.0000x reference)
//
#include <hip/hip_runtime.h>
#include <math.h>

#define NV 10000
#define B 512
#define L 256
#define E 64

typedef _Float16 f16;
typedef _Float16 f16x8 __attribute__((ext_vector_type(8)));
typedef float f32x4 __attribute__((ext_vector_type(4)));
typedef int v8i __attribute__((ext_vector_type(8)));

// ws layout (f32 offsets)
#define OFF_WA1HT 0u         // [256][256] f32  Wa1hT[k*256+j] = Wa1[j*512+k]
#define OFF_WC1T  65536u     // [256][256] f32
#define OFF_WB    131072u    // 262144 B: fp8 frags of 8*log2e*W_hh for mfma_scale 16x16x128
#define OFF_WIHF  196608u    // 262144 f16: frags of W_ih (16x16x32 f16 layout)
#define OFF_WA1NF 327680u    // 65536 f16: frags of Wa1n
#define OFF_PEMB  360448u    // 10,240,000 f32: P_perm[v][hc*4+q] = log2e*(ge@W_ih^T+b)[v][q*256+hc]
#define OFF_AEMB  10600448u  // 2,560,000 f16: A_emb[v][256]
// total 11,880,448 f32 = 47.5 MB

#define LOG2E 1.44269504f

__device__ __forceinline__ int fp8_byte(float x) {
  return __builtin_amdgcn_cvt_pk_fp8_f32(x, x, 0, false) & 0xFF;
}

// A-scale 120 = 2^-7: G = log2e*(P + h·W). Gates use exp2f directly
// (v_exp_f32 IS 2^x) -- the log2e mul is folded into W_hh/P at prep time.
#define MFMA_SC(a, b, c) \
  __builtin_amdgcn_mfma_scale_f32_16x16x128_f8f6f4((a), (b), (c), 0, 0, 0, 120, 0, 127)

__global__ __launch_bounds__(256) void k_prep(
    const float* __restrict__ W_ih, const float* __restrict__ W_hh,
    const float* __restrict__ Wa1, const float* __restrict__ Wc1,
    float* __restrict__ ws) {
  int idx = blockIdx.x * 256 + threadIdx.x;
  if (idx < 65536) {  // W_hh fp8 frags (x8) for 16x16x128: dword idx
    int d = idx & 7, lane = (idx >> 3) & 63, kt = (idx >> 9) & 1;
    int q = (idx >> 10) & 3, w = (idx >> 12) & 15;
    int l15 = lane & 15, quad = lane >> 4;
    int n = q * 256 + w * 16 + l15;
    int kb = kt * 128 + quad * 32 + d * 4;
    unsigned int word = 0;
#pragma unroll
    for (int jb = 0; jb < 4; ++jb)
      word |= ((unsigned int)fp8_byte(W_hh[n * 256 + kb + jb] * (8.f * LOG2E))) << (8 * jb);
    ((unsigned int*)(ws + OFF_WB))[idx] = word;
    return;
  }
  int p1 = idx - 65536;
  if (p1 < 262144) {  // W_ih f16 frags (16x16x32 layout, for k_pemb)
    int j = p1 & 7, lane = (p1 >> 3) & 63, kt = (p1 >> 9) & 7;
    int q = (p1 >> 12) & 3, w = (p1 >> 14) & 15;
    int n = q * 256 + w * 16 + (lane & 15);
    int k = kt * 32 + (lane >> 4) * 8 + j;
    ((f16*)(ws + OFF_WIHF))[p1] = (f16)W_ih[n * 256 + k];
    return;
  }
  int p2 = p1 - 262144;
  if (p2 < 65536) {  // Wa1n f16 frags
    int j = p2 & 7, lane = (p2 >> 3) & 63, kt = (p2 >> 9) & 7, w = (p2 >> 12) & 15;
    int n = w * 16 + (lane & 15);
    int k = kt * 32 + (lane >> 4) * 8 + j;
    ((f16*)(ws + OFF_WA1NF))[p2] = (f16)Wa1[n * 512 + 256 + k];
    return;
  }
  int i2 = p2 - 65536;
  if (i2 < 65536) {  // actor/critic transposes
    int k = i2 >> 8, j = i2 & 255;
    ws[OFF_WA1HT + i2] = Wa1[j * 512 + k];
    ws[OFF_WC1T + i2] = Wc1[j * 256 + k];
  }
}

// Fused P_emb + A_emb via f16 MFMA. 48 vertices/block, 209 blocks.
__global__ __launch_bounds__(1024) void k_pemb(
    const float* __restrict__ ge, const float* __restrict__ b_ih,
    const float* __restrict__ b_hh, float* __restrict__ ws) {
  __shared__ f16 Alds[48 * 264];
  const int tid = threadIdx.x, w = tid >> 6, lane = tid & 63;
  const int l15 = lane & 15, quad = lane >> 4;
  const int vbase = blockIdx.x * 48;
  for (int i = tid; i < 48 * 64; i += 1024) {
    int row = i >> 6, c4 = (i & 63) << 2;
    int v = min(vbase + row, NV - 1);
    const f32x4 g = *(const f32x4*)(ge + (size_t)v * 256 + c4);
    Alds[row * 264 + c4 + 0] = (f16)g[0];
    Alds[row * 264 + c4 + 1] = (f16)g[1];
    Alds[row * 264 + c4 + 2] = (f16)g[2];
    Alds[row * 264 + c4 + 3] = (f16)g[3];
  }
  __syncthreads();
  const f16* __restrict__ WIHF = (const f16*)(ws + OFF_WIHF);
  const f16* __restrict__ WANF = (const f16*)(ws + OFF_WA1NF);
  f32x4 Cp[3][4], Ca[3];
#pragma unroll
  for (int t = 0; t < 3; ++t) {
    Ca[t] = (f32x4){0.f, 0.f, 0.f, 0.f};
#pragma unroll
    for (int q = 0; q < 4; ++q) Cp[t][q] = (f32x4){0.f, 0.f, 0.f, 0.f};
  }
#pragma unroll
  for (int kt = 0; kt < 8; ++kt) {
    f16x8 a[3];
#pragma unroll
    for (int t = 0; t < 3; ++t)
      a[t] = *(const f16x8*)(Alds + (t * 16 + l15) * 264 + kt * 32 + quad * 8);
#pragma unroll
    for (int q = 0; q < 4; ++q) {
      f16x8 bq = *(const f16x8*)(WIHF + (size_t)(((w * 4 + q) * 8 + kt) * 512 + lane * 8));
#pragma unroll
      for (int t = 0; t < 3; ++t)
        Cp[t][q] = __builtin_amdgcn_mfma_f32_16x16x32_f16(a[t], bq, Cp[t][q], 0, 0, 0);
    }
    f16x8 bn = *(const f16x8*)(WANF + (size_t)((w * 8 + kt) * 512 + lane * 8));
#pragma unroll
    for (int t = 0; t < 3; ++t)
      Ca[t] = __builtin_amdgcn_mfma_f32_16x16x32_f16(a[t], bn, Ca[t], 0, 0, 0);
  }
  const int hc = w * 16 + l15;
  float bias[4];
#pragma unroll
  for (int q = 0; q < 4; ++q) {
    int n = q * 256 + hc;
    bias[q] = b_ih[n] + b_hh[n];
  }
  float* __restrict__ P = ws + OFF_PEMB;
  f16* __restrict__ A = (f16*)(ws + OFF_AEMB);
#pragma unroll
  for (int t = 0; t < 3; ++t)
#pragma unroll
    for (int reg = 0; reg < 4; ++reg) {
      int v = vbase + t * 16 + quad * 4 + reg;
      if (v < NV) {
        f32x4 pw;
#pragma unroll
        for (int q = 0; q < 4; ++q) pw[q] = LOG2E * (Cp[t][q][reg] + bias[q]);
        *(f32x4*)(P + (size_t)v * 1024 + hc * 4) = pw;
        A[(size_t)v * 256 + hc] = (f16)Ca[t][reg];
      }
    }
}

// LSTM + fused heads: 256 blocks x 1024 threads (16 waves), 2 paths/block.
// R9 structure exactly (plain t-loop, hA[t&1]) + log2e fold with std exp2f.
// (R11's NaN: raw __builtin_amdgcn_exp2f + lambda-unroll bundle -- both
// dropped; exp2f -> OCML -> v_exp_f32 with verified edge semantics.)
__global__ __launch_bounds__(1024) void k_lstm(
    const int* __restrict__ paths, const int* __restrict__ path_lens,
    const int* __restrict__ neighbors, const int* __restrict__ n_nb,
    const float* __restrict__ ba1, const float* __restrict__ Wa2,
    const float* __restrict__ ba2, const float* __restrict__ bc1,
    const float* __restrict__ Wc2, const float* __restrict__ bc2,
    float* __restrict__ out, float* __restrict__ ws) {
  const int tid = threadIdx.x, w = tid >> 6, lane = tid & 63;
  const int l15 = lane & 15, quad = lane >> 4;
  const int g2 = blockIdx.x * 2;

  __shared__ char hA[2][4 * 272];    // [parity][phys*272 + k] fp8
  __shared__ int vtx[2][260];        // staged path vertex ids, clamp-extended
  __shared__ float hfin[2][257];
  __shared__ float u_s[2][264];      // padded: index j + (j>>5)
  __shared__ float vred[2][256];
  __shared__ float part8[2][64][9];  // padded stride 9

  for (int i = tid; i < 2 * 4 * 272 / 4; i += 1024) ((int*)hA)[i] = 0;
  for (int i = tid; i < 2 * 260; i += 1024) {
    const int p = i >= 260, tt = i - p * 260;
    vtx[p][tt] = paths[(g2 + p) * L + min(tt, L - 1)];
  }

  const int len0 = path_lens[g2], len1 = path_lens[g2 + 1];
  const int lmax = max(len0, len1);

  // persistent B-frags for mfma_scale 16x16x128 (64 VGPR)
  const v8i* __restrict__ WBv = (const v8i*)(ws + OFF_WB);
  v8i Bf[4][2];
#pragma unroll
  for (int q = 0; q < 4; ++q)
#pragma unroll
    for (int kt = 0; kt < 2; ++kt)
      Bf[q][kt] = WBv[(size_t)(((w * 4 + q) * 2 + kt) * 64 + lane)];

  const char* __restrict__ Pb = (const char*)(ws + OFF_PEMB);
  const int hc = w * 16 + l15;
  const int path = quad >> 1;            // 0,0,1,1 per quad
  const int lenv = path ? len1 : len0;
  const unsigned loff = (unsigned)hc * 16u;
  const int physr = ((l15 >> 3) << 1) | (l15 & 1);  // A-read phys row

  float cst = 0.f, hst = 0.f;
  f32x4 Cf[4];
#pragma unroll
  for (int q = 0; q < 4; ++q) Cf[q] = (f32x4){0.f, 0.f, 0.f, 0.f};
  __syncthreads();

  // P prefetch: pv = P row for step t; vn = vertex id for step t+1 (from LDS)
  f32x4 pv = *(const f32x4*)(Pb + (unsigned)vtx[path][0] * 4096u + loff);
  int vn = vtx[path][1];

  for (int t = 0; t < lmax; ++t) {
    // a-frags first
    const char* hp = hA[t & 1];
    const v8i a0 = *(const v8i*)(hp + physr * 272 + quad * 32);
    const v8i a1 = *(const v8i*)(hp + physr * 272 + 128 + quad * 32);
    const int vn2 = vtx[path][t + 2];

    // next-step P prefetch (stays in flight across the raw barrier)
    const f32x4 pvn = *(const f32x4*)(Pb + (unsigned)vn * 4096u + loff);

    // ---- q0: input gate ----
    Cf[0][0] = pv[0]; Cf[0][1] = 0.f;
    Cf[0] = MFMA_SC(a0, Bf[0][0], Cf[0]);
    Cf[0] = MFMA_SC(a1, Bf[0][1], Cf[0]);
    const float si = __builtin_amdgcn_rcpf(1.f + exp2f(-(Cf[0][0] + Cf[0][1])));

    // ---- q1: forget gate ----
    Cf[1][0] = pv[1]; Cf[1][1] = 0.f;
    Cf[1] = MFMA_SC(a0, Bf[1][0], Cf[1]);
    Cf[1] = MFMA_SC(a1, Bf[1][1], Cf[1]);
    const float sf = __builtin_amdgcn_rcpf(1.f + exp2f(-(Cf[1][0] + Cf[1][1])));

    // ---- q2: cell candidate (tanh) ----
    Cf[2][0] = pv[2]; Cf[2][1] = 0.f;
    Cf[2] = MFMA_SC(a0, Bf[2][0], Cf[2]);
    Cf[2] = MFMA_SC(a1, Bf[2][1], Cf[2]);
    const float tg = 1.f - 2.f * __builtin_amdgcn_rcpf(
        exp2f(2.f * (Cf[2][0] + Cf[2][1])) + 1.f);

    // ---- q3: output gate ----
    Cf[3][0] = pv[3]; Cf[3][1] = 0.f;
    Cf[3] = MFMA_SC(a0, Bf[3][0], Cf[3]);
    Cf[3] = MFMA_SC(a1, Bf[3][1], Cf[3]);
    const float so = __builtin_amdgcn_rcpf(1.f + exp2f(-(Cf[3][0] + Cf[3][1])));

    const float cn = sf * cst + si * tg;
    const float hn = so * (1.f - 2.f * __builtin_amdgcn_rcpf(
        exp2f((2.f * LOG2E) * cn) + 1.f));
    if (t < lenv) { cst = cn; hst = hn; }

    if (!(quad & 1)) {  // quad0 -> phys 0,1 (path0); quad2 -> phys 2,3 (path1)
      char* nh = hA[(t + 1) & 1];
      const int hi = fp8_byte(16.f * hst);
      const float d = __builtin_amdgcn_cvt_f32_fp8(hi, 0);
      const int lo = fp8_byte(16.f * hst - d);
      nh[(path * 2 + 0) * 272 + hc] = (char)hi;
      nh[(path * 2 + 1) * 272 + hc] = (char)lo;
    }
    pv = pvn;
    vn = vn2;
    // raw barrier: fence LDS only, leave the global P prefetch in flight
    __builtin_amdgcn_sched_barrier(0);
    asm volatile("s_waitcnt lgkmcnt(0)" ::: "memory");
    __builtin_amdgcn_s_barrier();
    __builtin_amdgcn_sched_barrier(0);
  }

  // ---- fused heads for this block's 2 paths ----
  if (!(quad & 1)) hfin[path][hc] = hst;
  __syncthreads();

  const float* __restrict__ Wa1hT = ws + OFF_WA1HT;
  const float* __restrict__ Wc1T = ws + OFF_WC1T;
  const int p = tid >> 9;          // 0..1
  const int jj = tid & 255;
  const int dup = (tid >> 8) & 1;  // 0: actor-hidden, 1: critic-hidden
  if (dup == 0) {
    float aa = ba1[jj];
    for (int k = 0; k < 256; ++k) aa += Wa1hT[k * 256 + jj] * hfin[p][k];
    u_s[p][jj + (jj >> 5)] = aa;
  } else {
    float cc = bc1[jj];
    for (int k = 0; k < 256; ++k) cc += Wc1T[k * 256 + jj] * hfin[p][k];
    cc = cc > 0.f ? cc : __expf(cc) - 1.f;
    vred[p][jj] = cc * Wc2[jj];
  }
  __syncthreads();
  if (tid < 128) {
    const int pp = tid >> 6, lp = tid & 63;
    float s = vred[pp][lp] + vred[pp][lp + 64] + vred[pp][lp + 128] + vred[pp][lp + 192];
#pragma unroll
    for (int d = 32; d > 0; d >>= 1) s += __shfl_xor(s, d, 64);
    if (lp == 0) out[B * E + g2 + pp] = s + bc2[0];
  }
  // actor logits: (pa, e, jh) -> 32-long j-chunk
  const f16* __restrict__ A = (const f16*)(ws + OFF_AEMB);
  const int pa = tid >> 9, e = (tid >> 3) & 63, jh = tid & 7;
  const int nbv = neighbors[(g2 + pa) * 64 + e];
  float s = 0.f;
  const f16x8* __restrict__ Arow = (const f16x8*)(A + (size_t)nbv * 256 + jh * 32);
#pragma unroll
  for (int jo = 0; jo < 4; ++jo) {
    const f16x8 av = Arow[jo];
#pragma unroll
    for (int u = 0; u < 8; ++u) {
      const int j = jh * 32 + jo * 8 + u;
      float a = u_s[pa][j + (j >> 5)] + (float)av[u];
      a = a > 0.f ? a : __expf(a) - 1.f;
      s += a * Wa2[j];
    }
  }
  part8[pa][e][jh] = s;
  __syncthreads();
  if (tid < 128) {
    const int pp = tid >> 6, ee = tid & 63;
    const int ne = n_nb[g2 + pp];
    const bool valid = ee < ne;
    float le = -1e30f;
    if (valid) {
      le = ba2[0];
#pragma unroll
      for (int r = 0; r < 8; ++r) le += part8[pp][ee][r];
    }
    float m = le;
#pragma unroll
    for (int d = 32; d > 0; d >>= 1) m = fmaxf(m, __shfl_xor(m, d, 64));
    float pe = valid ? __expf(le - m) : 0.f;
    float sm = pe;
#pragma unroll
    for (int d = 32; d > 0; d >>= 1) sm += __shfl_xor(sm, d, 64);
    out[(g2 + pp) * 64 + ee] = pe / sm;
  }
}

extern "C" void kernel_launch(void* const* d_in, const int* in_sizes, int n_in,
                              void* d_out, int out_size, void* d_ws, size_t ws_size,
                              hipStream_t stream) {
  (void)in_sizes; (void)n_in; (void)out_size; (void)ws_size;
  const float* graph_emb = (const float*)d_in[0];
  const int* paths       = (const int*)d_in[1];
  const int* path_lens   = (const int*)d_in[2];
  const int* neighbors   = (const int*)d_in[3];
  const int* n_nb        = (const int*)d_in[4];
  const float* W_ih = (const float*)d_in[5];
  const float* W_hh = (const float*)d_in[6];
  const float* b_ih = (const float*)d_in[7];
  const float* b_hh = (const float*)d_in[8];
  const float* Wa1  = (const float*)d_in[9];
  const float* ba1  = (const float*)d_in[10];
  const float* Wa2  = (const float*)d_in[11];
  const float* ba2  = (const float*)d_in[12];
  const float* Wc1  = (const float*)d_in[13];
  const float* bc1  = (const float*)d_in[14];
  const float* Wc2  = (const float*)d_in[15];
  const float* bc2  = (const float*)d_in[16];
  float* out = (float*)d_out;
  float* ws = (float*)d_ws;

  hipLaunchKernelGGL(k_prep, dim3(1792), dim3(256), 0, stream, W_ih, W_hh, Wa1, Wc1, ws);
  hipLaunchKernelGGL(k_pemb, dim3(209), dim3(1024), 0, stream, graph_emb, b_ih, b_hh, ws);
  hipLaunchKernelGGL(k_lstm, dim3(256), dim3(1024), 0, stream, paths, path_lens,
                     neighbors, n_nb, ba1, Wa2, ba2, bc1, Wc2, bc2, out, ws);
}

// Round 13
// 345.463 us; speedup vs baseline: 1.0896x; 1.0896x over previous
//
#include <hip/hip_runtime.h>
#include <math.h>

#define NV 10000
#define B 512
#define L 256
#define E 64

typedef _Float16 f16;
typedef _Float16 f16x8 __attribute__((ext_vector_type(8)));
typedef float f32x4 __attribute__((ext_vector_type(4)));
typedef int v8i __attribute__((ext_vector_type(8)));

// ws layout (f32 offsets)
#define OFF_WA1HT 0u         // [256][256] f32  Wa1hT[k*256+j] = Wa1[j*512+k]
#define OFF_WC1T  65536u     // [256][256] f32
#define OFF_WB    131072u    // 262144 B: fp8 frags of 8*W_hh for mfma_scale 16x16x128
#define OFF_WIHF  196608u    // 262144 f16: frags of W_ih (16x16x32 f16 layout)
#define OFF_WA1NF 327680u    // 65536 f16: frags of Wa1n
#define OFF_PEMB  360448u    // 10,240,000 f32: P_perm[v][hc*4+q] = (ge@W_ih^T+b)[v][q*256+hc]
#define OFF_AEMB  10600448u  // 2,560,000 f16: A_emb[v][256]
// total 11,880,448 f32 = 47.5 MB

__device__ __forceinline__ int fp8_byte(float x) {
  return __builtin_amdgcn_cvt_pk_fp8_f32(x, x, 0, false) & 0xFF;
}

// A-scale 120 = 2^-7 folds the /128 gate normalization into the MFMA:
// G = P + (16h · 8W)/128 = P + h·W  (P stored UNSCALED)
#define MFMA_SC(a, b, c) \
  __builtin_amdgcn_mfma_scale_f32_16x16x128_f8f6f4((a), (b), (c), 0, 0, 0, 120, 0, 127)

__global__ __launch_bounds__(256) void k_prep(
    const float* __restrict__ W_ih, const float* __restrict__ W_hh,
    const float* __restrict__ Wa1, const float* __restrict__ Wc1,
    float* __restrict__ ws) {
  int idx = blockIdx.x * 256 + threadIdx.x;
  if (idx < 65536) {  // W_hh fp8 frags (x8) for 16x16x128: dword idx
    int d = idx & 7, lane = (idx >> 3) & 63, kt = (idx >> 9) & 1;
    int q = (idx >> 10) & 3, w = (idx >> 12) & 15;
    int l15 = lane & 15, quad = lane >> 4;
    int n = q * 256 + w * 16 + l15;
    int kb = kt * 128 + quad * 32 + d * 4;
    unsigned int word = 0;
#pragma unroll
    for (int jb = 0; jb < 4; ++jb)
      word |= ((unsigned int)fp8_byte(W_hh[n * 256 + kb + jb] * 8.f)) << (8 * jb);
    ((unsigned int*)(ws + OFF_WB))[idx] = word;
    return;
  }
  int p1 = idx - 65536;
  if (p1 < 262144) {  // W_ih f16 frags (16x16x32 layout, for k_pemb)
    int j = p1 & 7, lane = (p1 >> 3) & 63, kt = (p1 >> 9) & 7;
    int q = (p1 >> 12) & 3, w = (p1 >> 14) & 15;
    int n = q * 256 + w * 16 + (lane & 15);
    int k = kt * 32 + (lane >> 4) * 8 + j;
    ((f16*)(ws + OFF_WIHF))[p1] = (f16)W_ih[n * 256 + k];
    return;
  }
  int p2 = p1 - 262144;
  if (p2 < 65536) {  // Wa1n f16 frags
    int j = p2 & 7, lane = (p2 >> 3) & 63, kt = (p2 >> 9) & 7, w = (p2 >> 12) & 15;
    int n = w * 16 + (lane & 15);
    int k = kt * 32 + (lane >> 4) * 8 + j;
    ((f16*)(ws + OFF_WA1NF))[p2] = (f16)Wa1[n * 512 + 256 + k];
    return;
  }
  int i2 = p2 - 65536;
  if (i2 < 65536) {  // actor/critic transposes
    int k = i2 >> 8, j = i2 & 255;
    ws[OFF_WA1HT + i2] = Wa1[j * 512 + k];
    ws[OFF_WC1T + i2] = Wc1[j * 256 + k];
  }
}

// Fused P_emb + A_emb via f16 MFMA. 48 vertices/block, 209 blocks.
__global__ __launch_bounds__(1024) void k_pemb(
    const float* __restrict__ ge, const float* __restrict__ b_ih,
    const float* __restrict__ b_hh, float* __restrict__ ws) {
  __shared__ f16 Alds[48 * 264];
  const int tid = threadIdx.x, w = tid >> 6, lane = tid & 63;
  const int l15 = lane & 15, quad = lane >> 4;
  const int vbase = blockIdx.x * 48;
  for (int i = tid; i < 48 * 64; i += 1024) {
    int row = i >> 6, c4 = (i & 63) << 2;
    int v = min(vbase + row, NV - 1);
    const f32x4 g = *(const f32x4*)(ge + (size_t)v * 256 + c4);
    Alds[row * 264 + c4 + 0] = (f16)g[0];
    Alds[row * 264 + c4 + 1] = (f16)g[1];
    Alds[row * 264 + c4 + 2] = (f16)g[2];
    Alds[row * 264 + c4 + 3] = (f16)g[3];
  }
  __syncthreads();
  const f16* __restrict__ WIHF = (const f16*)(ws + OFF_WIHF);
  const f16* __restrict__ WANF = (const f16*)(ws + OFF_WA1NF);
  f32x4 Cp[3][4], Ca[3];
#pragma unroll
  for (int t = 0; t < 3; ++t) {
    Ca[t] = (f32x4){0.f, 0.f, 0.f, 0.f};
#pragma unroll
    for (int q = 0; q < 4; ++q) Cp[t][q] = (f32x4){0.f, 0.f, 0.f, 0.f};
  }
#pragma unroll
  for (int kt = 0; kt < 8; ++kt) {
    f16x8 a[3];
#pragma unroll
    for (int t = 0; t < 3; ++t)
      a[t] = *(const f16x8*)(Alds + (t * 16 + l15) * 264 + kt * 32 + quad * 8);
#pragma unroll
    for (int q = 0; q < 4; ++q) {
      f16x8 bq = *(const f16x8*)(WIHF + (size_t)(((w * 4 + q) * 8 + kt) * 512 + lane * 8));
#pragma unroll
      for (int t = 0; t < 3; ++t)
        Cp[t][q] = __builtin_amdgcn_mfma_f32_16x16x32_f16(a[t], bq, Cp[t][q], 0, 0, 0);
    }
    f16x8 bn = *(const f16x8*)(WANF + (size_t)((w * 8 + kt) * 512 + lane * 8));
#pragma unroll
    for (int t = 0; t < 3; ++t)
      Ca[t] = __builtin_amdgcn_mfma_f32_16x16x32_f16(a[t], bn, Ca[t], 0, 0, 0);
  }
  const int hc = w * 16 + l15;
  float bias[4];
#pragma unroll
  for (int q = 0; q < 4; ++q) {
    int n = q * 256 + hc;
    bias[q] = b_ih[n] + b_hh[n];
  }
  float* __restrict__ P = ws + OFF_PEMB;
  f16* __restrict__ A = (f16*)(ws + OFF_AEMB);
#pragma unroll
  for (int t = 0; t < 3; ++t)
#pragma unroll
    for (int reg = 0; reg < 4; ++reg) {
      int v = vbase + t * 16 + quad * 4 + reg;
      if (v < NV) {
        f32x4 pw;
#pragma unroll
        for (int q = 0; q < 4; ++q) pw[q] = Cp[t][q][reg] + bias[q];  // unscaled
        *(f32x4*)(P + (size_t)v * 1024 + hc * 4) = pw;
        A[(size_t)v * 256 + hc] = (f16)Ca[t][reg];
      }
    }
}

// LSTM + fused heads: 256 blocks x 1024 threads (16 waves), 2 paths/block.
// R9 build (measured best: k_lstm 259us, total 346us). Per-gate chunks,
// no sched pins, scale-fold 2^-7, __expf gates. Structural floor analysis:
// 2430 cy/step = 1104 MFMA (invariant matrix floor) + ~650 serial gate VALU
// + ~450 LDS + ~230 barrier; interleave/pins/setprio/wave-count/layout all
// measured null-to-negative (R3-R8); exp2 routes slower or incorrect (R11/12).
__global__ __launch_bounds__(1024) void k_lstm(
    const int* __restrict__ paths, const int* __restrict__ path_lens,
    const int* __restrict__ neighbors, const int* __restrict__ n_nb,
    const float* __restrict__ ba1, const float* __restrict__ Wa2,
    const float* __restrict__ ba2, const float* __restrict__ bc1,
    const float* __restrict__ Wc2, const float* __restrict__ bc2,
    float* __restrict__ out, float* __restrict__ ws) {
  const int tid = threadIdx.x, w = tid >> 6, lane = tid & 63;
  const int l15 = lane & 15, quad = lane >> 4;
  const int g2 = blockIdx.x * 2;

  __shared__ char hA[2][4 * 272];    // [parity][phys*272 + k] fp8
  __shared__ int vtx[2][260];        // staged path vertex ids, clamp-extended
  __shared__ float hfin[2][257];
  __shared__ float u_s[2][264];      // padded: index j + (j>>5)
  __shared__ float vred[2][256];
  __shared__ float part8[2][64][9];  // padded stride 9

  for (int i = tid; i < 2 * 4 * 272 / 4; i += 1024) ((int*)hA)[i] = 0;
  for (int i = tid; i < 2 * 260; i += 1024) {
    const int p = i >= 260, tt = i - p * 260;
    vtx[p][tt] = paths[(g2 + p) * L + min(tt, L - 1)];
  }

  const int len0 = path_lens[g2], len1 = path_lens[g2 + 1];
  const int lmax = max(len0, len1);

  // persistent B-frags for mfma_scale 16x16x128 (64 VGPR)
  const v8i* __restrict__ WBv = (const v8i*)(ws + OFF_WB);
  v8i Bf[4][2];
#pragma unroll
  for (int q = 0; q < 4; ++q)
#pragma unroll
    for (int kt = 0; kt < 2; ++kt)
      Bf[q][kt] = WBv[(size_t)(((w * 4 + q) * 2 + kt) * 64 + lane)];

  const char* __restrict__ Pb = (const char*)(ws + OFF_PEMB);
  const int hc = w * 16 + l15;
  const int path = quad >> 1;            // 0,0,1,1 per quad
  const int lenv = path ? len1 : len0;
  const unsigned loff = (unsigned)hc * 16u;
  const int physr = ((l15 >> 3) << 1) | (l15 & 1);  // A-read phys row

  float cst = 0.f, hst = 0.f;
  f32x4 Cf[4];
#pragma unroll
  for (int q = 0; q < 4; ++q) Cf[q] = (f32x4){0.f, 0.f, 0.f, 0.f};
  __syncthreads();

  // P prefetch: pv = P row for step t; vn = vertex id for step t+1 (from LDS)
  f32x4 pv = *(const f32x4*)(Pb + (unsigned)vtx[path][0] * 4096u + loff);
  int vn = vtx[path][1];

  for (int t = 0; t < lmax; ++t) {
    // a-frags first
    const char* hp = hA[t & 1];
    const v8i a0 = *(const v8i*)(hp + physr * 272 + quad * 32);
    const v8i a1 = *(const v8i*)(hp + physr * 272 + 128 + quad * 32);
    const int vn2 = vtx[path][t + 2];

    // next-step P prefetch (stays in flight across the raw barrier)
    const f32x4 pvn = *(const f32x4*)(Pb + (unsigned)vn * 4096u + loff);

    // ---- q0: input gate ----
    Cf[0][0] = pv[0]; Cf[0][1] = 0.f;
    Cf[0] = MFMA_SC(a0, Bf[0][0], Cf[0]);
    Cf[0] = MFMA_SC(a1, Bf[0][1], Cf[0]);
    const float si = __builtin_amdgcn_rcpf(1.f + __expf(-(Cf[0][0] + Cf[0][1])));

    // ---- q1: forget gate ----
    Cf[1][0] = pv[1]; Cf[1][1] = 0.f;
    Cf[1] = MFMA_SC(a0, Bf[1][0], Cf[1]);
    Cf[1] = MFMA_SC(a1, Bf[1][1], Cf[1]);
    const float sf = __builtin_amdgcn_rcpf(1.f + __expf(-(Cf[1][0] + Cf[1][1])));

    // ---- q2: cell candidate (tanh) ----
    Cf[2][0] = pv[2]; Cf[2][1] = 0.f;
    Cf[2] = MFMA_SC(a0, Bf[2][0], Cf[2]);
    Cf[2] = MFMA_SC(a1, Bf[2][1], Cf[2]);
    const float tg = 1.f - 2.f * __builtin_amdgcn_rcpf(
        __expf(2.f * (Cf[2][0] + Cf[2][1])) + 1.f);

    // ---- q3: output gate ----
    Cf[3][0] = pv[3]; Cf[3][1] = 0.f;
    Cf[3] = MFMA_SC(a0, Bf[3][0], Cf[3]);
    Cf[3] = MFMA_SC(a1, Bf[3][1], Cf[3]);
    const float so = __builtin_amdgcn_rcpf(1.f + __expf(-(Cf[3][0] + Cf[3][1])));

    const float cn = sf * cst + si * tg;
    const float hn = so * (1.f - 2.f * __builtin_amdgcn_rcpf(__expf(2.f * cn) + 1.f));
    if (t < lenv) { cst = cn; hst = hn; }

    if (!(quad & 1)) {  // quad0 -> phys 0,1 (path0); quad2 -> phys 2,3 (path1)
      char* nh = hA[(t + 1) & 1];
      const int hi = fp8_byte(16.f * hst);
      const float d = __builtin_amdgcn_cvt_f32_fp8(hi, 0);
      const int lo = fp8_byte(16.f * hst - d);
      nh[(path * 2 + 0) * 272 + hc] = (char)hi;
      nh[(path * 2 + 1) * 272 + hc] = (char)lo;
    }
    pv = pvn;
    vn = vn2;
    // raw barrier: fence LDS only, leave the global P prefetch in flight
    __builtin_amdgcn_sched_barrier(0);
    asm volatile("s_waitcnt lgkmcnt(0)" ::: "memory");
    __builtin_amdgcn_s_barrier();
    __builtin_amdgcn_sched_barrier(0);
  }

  // ---- fused heads for this block's 2 paths ----
  if (!(quad & 1)) hfin[path][hc] = hst;
  __syncthreads();

  const float* __restrict__ Wa1hT = ws + OFF_WA1HT;
  const float* __restrict__ Wc1T = ws + OFF_WC1T;
  const int p = tid >> 9;          // 0..1
  const int jj = tid & 255;
  const int dup = (tid >> 8) & 1;  // 0: actor-hidden, 1: critic-hidden
  if (dup == 0) {
    float aa = ba1[jj];
    for (int k = 0; k < 256; ++k) aa += Wa1hT[k * 256 + jj] * hfin[p][k];
    u_s[p][jj + (jj >> 5)] = aa;
  } else {
    float cc = bc1[jj];
    for (int k = 0; k < 256; ++k) cc += Wc1T[k * 256 + jj] * hfin[p][k];
    cc = cc > 0.f ? cc : __expf(cc) - 1.f;
    vred[p][jj] = cc * Wc2[jj];
  }
  __syncthreads();
  if (tid < 128) {
    const int pp = tid >> 6, lp = tid & 63;
    float s = vred[pp][lp] + vred[pp][lp + 64] + vred[pp][lp + 128] + vred[pp][lp + 192];
#pragma unroll
    for (int d = 32; d > 0; d >>= 1) s += __shfl_xor(s, d, 64);
    if (lp == 0) out[B * E + g2 + pp] = s + bc2[0];
  }
  // actor logits: (pa, e, jh) -> 32-long j-chunk
  const f16* __restrict__ A = (const f16*)(ws + OFF_AEMB);
  const int pa = tid >> 9, e = (tid >> 3) & 63, jh = tid & 7;
  const int nbv = neighbors[(g2 + pa) * 64 + e];
  float s = 0.f;
  const f16x8* __restrict__ Arow = (const f16x8*)(A + (size_t)nbv * 256 + jh * 32);
#pragma unroll
  for (int jo = 0; jo < 4; ++jo) {
    const f16x8 av = Arow[jo];
#pragma unroll
    for (int u = 0; u < 8; ++u) {
      const int j = jh * 32 + jo * 8 + u;
      float a = u_s[pa][j + (j >> 5)] + (float)av[u];
      a = a > 0.f ? a : __expf(a) - 1.f;
      s += a * Wa2[j];
    }
  }
  part8[pa][e][jh] = s;
  __syncthreads();
  if (tid < 128) {
    const int pp = tid >> 6, ee = tid & 63;
    const int ne = n_nb[g2 + pp];
    const bool valid = ee < ne;
    float le = -1e30f;
    if (valid) {
      le = ba2[0];
#pragma unroll
      for (int r = 0; r < 8; ++r) le += part8[pp][ee][r];
    }
    float m = le;
#pragma unroll
    for (int d = 32; d > 0; d >>= 1) m = fmaxf(m, __shfl_xor(m, d, 64));
    float pe = valid ? __expf(le - m) : 0.f;
    float sm = pe;
#pragma unroll
    for (int d = 32; d > 0; d >>= 1) sm += __shfl_xor(sm, d, 64);
    out[(g2 + pp) * 64 + ee] = pe / sm;
  }
}

extern "C" void kernel_launch(void* const* d_in, const int* in_sizes, int n_in,
                              void* d_out, int out_size, void* d_ws, size_t ws_size,
                              hipStream_t stream) {
  (void)in_sizes; (void)n_in; (void)out_size; (void)ws_size;
  const float* graph_emb = (const float*)d_in[0];
  const int* paths       = (const int*)d_in[1];
  const int* path_lens   = (const int*)d_in[2];
  const int* neighbors   = (const int*)d_in[3];
  const int* n_nb        = (const int*)d_in[4];
  const float* W_ih = (const float*)d_in[5];
  const float* W_hh = (const float*)d_in[6];
  const float* b_ih = (const float*)d_in[7];
  const float* b_hh = (const float*)d_in[8];
  const float* Wa1  = (const float*)d_in[9];
  const float* ba1  = (const float*)d_in[10];
  const float* Wa2  = (const float*)d_in[11];
  const float* ba2  = (const float*)d_in[12];
  const float* Wc1  = (const float*)d_in[13];
  const float* bc1  = (const float*)d_in[14];
  const float* Wc2  = (const float*)d_in[15];
  const float* bc2  = (const float*)d_in[16];
  float* out = (float*)d_out;
  float* ws = (float*)d_ws;

  hipLaunchKernelGGL(k_prep, dim3(1792), dim3(256), 0, stream, W_ih, W_hh, Wa1, Wc1, ws);
  hipLaunchKernelGGL(k_pemb, dim3(209), dim3(1024), 0, stream, graph_emb, b_ih, b_hh, ws);
  hipLaunchKernelGGL(k_lstm, dim3(256), dim3(1024), 0, stream, paths, path_lens,
                     neighbors, n_nb, ba1, Wa2, ba2, bc1, Wc2, bc2, out, ws);
}